// Round 11
// baseline (74.938 us; speedup 1.0000x reference)
//
#include <hip/hip_runtime.h>

#define F 32

// ---- bf16 helpers (manual, RNE) -------------------------------------------
__device__ __forceinline__ unsigned int f2bf_rne(float f) {
    unsigned int u = __float_as_uint(f);
    return (u + 0x7fffu + ((u >> 16) & 1u)) >> 16;          // bf16 bits in low 16
}
__device__ __forceinline__ float bf_lo(unsigned int u) { return __uint_as_float(u << 16); }
__device__ __forceinline__ float bf_hi(unsigned int u) { return __uint_as_float(u & 0xffff0000u); }

// ---------------------------------------------------------------------------
// Prep (fused, 2 block ranges):
//  [0, gxw):   y = x @ W -> bf16-pair packed [n][16 uints] (6.4 MB).
//              lane = node; W via unroll-const indexing -> scalarized s_loads.
//  [gxw, ...): zero d_out (harness poisons it; spmm accumulates via atomics).
// NOTE: row_ptr build is GONE — edge-centric spmm reads rows[] directly.
// ---------------------------------------------------------------------------
__global__ void prep_kernel(const float* __restrict__ x, const float* __restrict__ w,
                            uint4* __restrict__ y4,
                            uint4* __restrict__ out_z,
                            int n_nodes, int n_out4, int gxw) {
    int b = blockIdx.x;
    if (b < gxw) {
        int n = b * blockDim.x + threadIdx.x;
        if (n >= n_nodes) return;
        const float4* xp = (const float4*)(x + (size_t)n * F);
        float xr[F];
#pragma unroll
        for (int j = 0; j < 8; ++j) {
            float4 t = xp[j];
            xr[4*j+0] = t.x; xr[4*j+1] = t.y; xr[4*j+2] = t.z; xr[4*j+3] = t.w;
        }
        float acc[F];
#pragma unroll
        for (int f = 0; f < F; ++f) acc[f] = 0.f;
#pragma unroll
        for (int k = 0; k < F; ++k) {
            float xk = xr[k];
#pragma unroll
            for (int f = 0; f < F; ++f)
                acc[f] = fmaf(xk, w[k * F + f], acc[f]);   // w uniform -> s_load
        }
        unsigned int op[16];
#pragma unroll
        for (int k = 0; k < 16; ++k)
            op[k] = f2bf_rne(acc[2*k]) | (f2bf_rne(acc[2*k+1]) << 16);
#pragma unroll
        for (int j = 0; j < 4; ++j)
            y4[(size_t)n * 4 + j] = make_uint4(op[4*j], op[4*j+1], op[4*j+2], op[4*j+3]);
    } else {
        int i = (b - gxw) * blockDim.x + threadIdx.x;
        if (i < n_out4) out_z[i] = make_uint4(0u, 0u, 0u, 0u);
    }
}

// ---------------------------------------------------------------------------
// SpMM v11 — EDGE-CENTRIC, perfectly balanced (R10 post-mortem: the gather
// floor is shape-invariant; remaining levers are balance + pass fusion).
// Each wave owns exactly 64 consecutive edges; 16-lane group g owns 16 of
// them, lane l = feature pair (2l,2l+1). rows[] is read directly (coalesced,
// fused — the separate row_ptr prep pass is eliminated). Within a group the
// 16 edges are segment-reduced over the sorted rows in registers; segment
// boundaries flush via fp32 atomicAdd (out pre-zeroed). ~2 flushes per chunk.
// Gathers: dword per lane, 16 back-to-back (v9's proven best shape).
// ---------------------------------------------------------------------------
__global__ void spmm_kernel(const unsigned int* __restrict__ y_u,
                            const int* __restrict__ cols,
                            const float* __restrict__ vals,
                            const int* __restrict__ rows,
                            float* __restrict__ out, int n_edges) {
    int gid   = blockIdx.x * blockDim.x + threadIdx.x;
    int tid   = threadIdx.x & 63;
    int l     = tid & 15;                    // feature-pair lane
    int gbase = tid & 48;                    // group's base lane in the wave
    long base = (long)(gid >> 6) * 64;       // wave's first edge

    int eidx = (int)base + tid;
    bool ok  = eidx < n_edges;
    int ecl  = ok ? eidx : (n_edges - 1);
    int   cB = cols[ecl];                    // one coalesced load per array
    int   rB = rows[ecl];
    float vB = ok ? vals[ecl] : 0.f;         // OOB -> +0 to a valid row

    // 16 independent gathers, issued back-to-back (16 lines in flight/group)
    unsigned int u[16];
#pragma unroll
    for (int j = 0; j < 16; ++j) {
        int c = __shfl(cB, gbase + j, 64);
        u[j] = y_u[(size_t)c * 16 + l];
    }

    float a0 = 0.f, a1 = 0.f;
    int rprev = __shfl(rB, gbase, 64);
#pragma unroll
    for (int j = 0; j < 16; ++j) {
        int   r = __shfl(rB, gbase + j, 64);
        float v = __shfl(vB, gbase + j, 64);
        if (r != rprev) {                    // uniform within group
            atomicAdd(&out[(size_t)rprev * F + 2 * l],     a0);
            atomicAdd(&out[(size_t)rprev * F + 2 * l + 1], a1);
            a0 = 0.f; a1 = 0.f; rprev = r;
        }
        a0 += bf_lo(u[j]) * v;
        a1 += bf_hi(u[j]) * v;
    }
    atomicAdd(&out[(size_t)rprev * F + 2 * l],     a0);
    atomicAdd(&out[(size_t)rprev * F + 2 * l + 1], a1);
}

// ---------------------------------------------------------------------------
extern "C" void kernel_launch(void* const* d_in, const int* in_sizes, int n_in,
                              void* d_out, int out_size, void* d_ws, size_t ws_size,
                              hipStream_t stream) {
    const float* x    = (const float*)d_in[0];
    const int*   rows = (const int*)d_in[1];
    const int*   cols = (const int*)d_in[2];
    const float* vals = (const float*)d_in[3];
    const float* w    = (const float*)d_in[4];

    int n_nodes = in_sizes[0] / F;   // 100000
    int n_edges = in_sizes[1];       // 1600000

    // ws: y [n_nodes * 4 uint4 = 6.4 MB]
    uint4* y4 = (uint4*)d_ws;

    int n_out4 = out_size / 4;                       // out as uint4 count
    int gxw = (n_nodes + 255) / 256;
    int gz  = (n_out4 + 255) / 256;
    prep_kernel<<<gxw + gz, 256, 0, stream>>>(x, w, y4, (uint4*)d_out,
                                              n_nodes, n_out4, gxw);

    long waves = ((long)n_edges + 63) / 64;
    int grid_spmm = (int)((waves * 64 + 255) / 256);
    spmm_kernel<<<grid_spmm, 256, 0, stream>>>((const unsigned int*)y4, cols, vals,
                                               rows, (float*)d_out, n_edges);
}

// Round 12
// 51.250 us; speedup vs baseline: 1.4622x; 1.4622x over previous
//
#include <hip/hip_runtime.h>

#define F 32

typedef float v2f __attribute__((ext_vector_type(2)));   // clang-native: nt-store OK

// ---- bf16 helpers (manual, RNE) -------------------------------------------
__device__ __forceinline__ unsigned int f2bf_rne(float f) {
    unsigned int u = __float_as_uint(f);
    return (u + 0x7fffu + ((u >> 16) & 1u)) >> 16;          // bf16 bits in low 16
}
__device__ __forceinline__ float bf_lo(unsigned int u) { return __uint_as_float(u << 16); }
__device__ __forceinline__ float bf_hi(unsigned int u) { return __uint_as_float(u & 0xffff0000u); }

// ---------------------------------------------------------------------------
// Prep (fused, 2 block ranges):
//  [0, gxw):   y = x @ W -> bf16-pair packed [n][16 uints] (6.4 MB).
//              lane = node; W via unroll-const indexing -> scalarized s_loads.
//  [gxw, ...): CSR row_ptr boundary fill, int4-vectorized (4 edges/thread,
//              1/4 the threads of the scalar version, same coalesced bytes).
// ---------------------------------------------------------------------------
__global__ void prep_kernel(const float* __restrict__ x, const float* __restrict__ w,
                            uint4* __restrict__ y4,
                            const int* __restrict__ rows,
                            int* __restrict__ row_ptr,
                            int n_nodes, int n_edges, int gxw) {
    int b = blockIdx.x;
    if (b < gxw) {
        int n = b * blockDim.x + threadIdx.x;
        if (n >= n_nodes) return;
        const float4* xp = (const float4*)(x + (size_t)n * F);
        float xr[F];
#pragma unroll
        for (int j = 0; j < 8; ++j) {
            float4 t = xp[j];
            xr[4*j+0] = t.x; xr[4*j+1] = t.y; xr[4*j+2] = t.z; xr[4*j+3] = t.w;
        }
        float acc[F];
#pragma unroll
        for (int f = 0; f < F; ++f) acc[f] = 0.f;
#pragma unroll
        for (int k = 0; k < F; ++k) {
            float xk = xr[k];
#pragma unroll
            for (int f = 0; f < F; ++f)
                acc[f] = fmaf(xk, w[k * F + f], acc[f]);   // w uniform -> s_load
        }
        unsigned int op[16];
#pragma unroll
        for (int k = 0; k < 16; ++k)
            op[k] = f2bf_rne(acc[2*k]) | (f2bf_rne(acc[2*k+1]) << 16);
#pragma unroll
        for (int j = 0; j < 4; ++j)
            y4[(size_t)n * 4 + j] = make_uint4(op[4*j], op[4*j+1], op[4*j+2], op[4*j+3]);
    } else {
        // 4 edges per thread: e .. e+3 (plus the e==n_edges sentinel by thread 0
        // of the tail). row_ptr[r] = first edge index with rows[e] >= r.
        int e = ((b - gxw) * blockDim.x + threadIdx.x) * 4;
        if (e >= n_edges) {
            if (e == ((n_edges + 3) & ~3)) {                 // one thread past end
                // handle sentinel range (rows[n_edges-1], n_nodes]
                int prev = rows[n_edges - 1];
                for (int r = prev + 1; r <= n_nodes; ++r) row_ptr[r] = n_edges;
            }
            return;
        }
        int prev = (e == 0) ? -1 : rows[e - 1];
        int last = min(e + 3, n_edges - 1);
        if (e + 3 <= n_edges - 1) {
            int4 rq = *(const int4*)(rows + e);
            int rr[4] = {rq.x, rq.y, rq.z, rq.w};
#pragma unroll
            for (int j = 0; j < 4; ++j) {
                int cur = rr[j];
                for (int r = prev + 1; r <= cur; ++r) row_ptr[r] = e + j;
                prev = cur;
            }
        } else {
            for (int k = e; k <= last; ++k) {
                int cur = rows[k];
                for (int r = prev + 1; r <= cur; ++r) row_ptr[r] = k;
                prev = cur;
            }
            // sentinel handled here if this thread covers the last edge
            for (int r = prev + 1; r <= n_nodes; ++r) row_ptr[r] = n_edges;
        }
    }
}

// ---------------------------------------------------------------------------
// SpMM (v9 structure — measured-best, reverted after v10/v11 regressions).
// 16-lane group per node, lane l = feature pair (2l, 2l+1).
// 16-edge batches: one coalesced cols/vals load per batch (nt), shfl
// broadcast (DS pipe), 16 independent dword gathers back-to-back (VMEM),
// FMA block (VALU). Tail: clamp gather idx to e1-1 (line already cached),
// zero v. Gather floor: ~1.6M random 64B lines ≈ 14 cy/line/CU (MSHR-bound).
// ---------------------------------------------------------------------------
__global__ void spmm_kernel(const unsigned int* __restrict__ y_u,
                            const int* __restrict__ cols,
                            const float* __restrict__ vals,
                            const int* __restrict__ row_ptr,
                            v2f* __restrict__ out2, int n_nodes) {
    int gid = blockIdx.x * blockDim.x + threadIdx.x;
    int n = gid >> 4;
    int l = gid & 15;
    if (n >= n_nodes) return;

    int e0 = row_ptr[n];
    int e1 = row_ptr[n + 1];
    float aL = 0.f, aH = 0.f;

    for (int base = e0; base < e1; base += 16) {
        int idx  = base + l;
        bool ok  = idx < e1;
        int idxc = ok ? idx : (e1 - 1);                  // e1>=1 whenever loop runs
        int   cB = __builtin_nontemporal_load(&cols[idxc]);
        float vB = ok ? __builtin_nontemporal_load(&vals[idxc]) : 0.f;

        unsigned int u[16];
#pragma unroll
        for (int j = 0; j < 16; ++j) {
            int c = __shfl(cB, j, 16);                   // DS pipe
            u[j] = y_u[(size_t)c * 16 + l];              // VMEM pipe, 16 in flight
        }
#pragma unroll
        for (int j = 0; j < 16; ++j) {
            float v = __shfl(vB, j, 16);
            aL += bf_lo(u[j]) * v;                       // VALU
            aH += bf_hi(u[j]) * v;
        }
    }
    v2f o; o[0] = aL; o[1] = aH;
    __builtin_nontemporal_store(o, &out2[(size_t)n * 16 + l]);
}

// ---------------------------------------------------------------------------
extern "C" void kernel_launch(void* const* d_in, const int* in_sizes, int n_in,
                              void* d_out, int out_size, void* d_ws, size_t ws_size,
                              hipStream_t stream) {
    const float* x    = (const float*)d_in[0];
    const int*   rows = (const int*)d_in[1];
    const int*   cols = (const int*)d_in[2];
    const float* vals = (const float*)d_in[3];
    const float* w    = (const float*)d_in[4];

    int n_nodes = in_sizes[0] / F;   // 100000
    int n_edges = in_sizes[1];       // 1600000

    // ws: y [n_nodes * 16 uints = 6.4 MB] | row_ptr [N+1]
    uint4* y4      = (uint4*)d_ws;
    int*   row_ptr = (int*)((char*)d_ws + (size_t)n_nodes * 16 * sizeof(unsigned int));

    int gxw = (n_nodes + 255) / 256;
    int gpe = ((n_edges + 3) / 4 + 1 + 255) / 256;       // 4 edges/thread + sentinel
    prep_kernel<<<gxw + gpe, 256, 0, stream>>>(x, w, y4, rows, row_ptr,
                                               n_nodes, n_edges, gxw);

    int grid_spmm = (n_nodes * 16 + 255) / 256;
    spmm_kernel<<<grid_spmm, 256, 0, stream>>>((const unsigned int*)y4, cols, vals,
                                               row_ptr, (v2f*)d_out, n_nodes);
}